// Round 2
// baseline (275.779 us; speedup 1.0000x reference)
//
#include <hip/hip_runtime.h>
#include <cstddef>

#define B_  16384
#define F_  2048
#define T_  64
#define C_  32
#define H_  24
#define HH_ 48
#define ROWS 256   // rows per block (1 per thread)

// ---------------------------------------------------------------------------
// Kernel A: one thread = one (b,t) row. W read via wave-uniform (scalar) loads
// from global; x row read as 8x float4 into registers (one 128-B line/row).
// No LDS except the 4-float block partial buffer.
// ---------------------------------------------------------------------------
__global__ __launch_bounds__(256) void kitnet_main(
    const float* __restrict__ x, const int* __restrict__ clusters,
    const float* __restrict__ Wt, const float* __restrict__ hb,
    const float* __restrict__ vb, float* __restrict__ sse)
{
    __shared__ float wsum[4];

    const int tid = threadIdx.x;
    const int t   = blockIdx.x & (T_ - 1);          // t fastest
    const int b   = (blockIdx.x >> 6) * ROWS + tid;

    const float* wt = Wt + t * (C_ * H_);           // uniform base
    const int*   cl = clusters + t * C_;

    // --- contiguity check (vector compare + ballot; cheap) ---
    const int col0 = cl[0];                          // uniform -> s_load
    const int myc  = cl[tid & (C_ - 1)];
    const bool okl = (myc == col0 + (tid & (C_ - 1)));
    const bool contig = (__ballot(okl) == ~0ULL) && ((col0 & 3) == 0);

    // --- load this row's 32 gathered values into registers ---
    float xv[C_];
    if (contig) {
        const float4* xr = (const float4*)(x + (size_t)b * F_ + col0);
        #pragma unroll
        for (int q = 0; q < C_ / 4; ++q) {
            const float4 v = xr[q];
            xv[q * 4 + 0] = v.x; xv[q * 4 + 1] = v.y;
            xv[q * 4 + 2] = v.z; xv[q * 4 + 3] = v.w;
        }
    } else {
        const float* xrow = x + (size_t)b * F_;
        #pragma unroll
        for (int c = 0; c < C_; ++c) xv[c] = xrow[cl[c]];   // cl[c] uniform
    }

    // --- stage 1: h = xv . Wt[t]   (W via scalar loads, one SGPR src per FMA)
    float h[H_];
    #pragma unroll
    for (int j = 0; j < H_; ++j) h[j] = hb[t * H_ + j];     // uniform

    #pragma unroll
    for (int c = 0; c < C_; ++c) {
        const float xc = xv[c];
        #pragma unroll
        for (int j = 0; j < H_; ++j) h[j] += wt[c * H_ + j] * xc;
    }

    // --- stage 2: out_c = h . Wt[t][c] + vb_c; err += (out_c - xv_c)^2 ---
    float err = 0.f;
    #pragma unroll
    for (int c = 0; c < C_; ++c) {
        float acc = vb[t * C_ + c];                          // uniform
        #pragma unroll
        for (int j = 0; j < H_; ++j) acc += h[j] * wt[c * H_ + j];
        const float d = acc - xv[c];
        err += d * d;
    }

    // --- reduce: wave shuffle -> block -> one atomic ---
    #pragma unroll
    for (int off = 32; off > 0; off >>= 1) err += __shfl_down(err, off, 64);
    if ((tid & 63) == 0) wsum[tid >> 6] = err;
    __syncthreads();
    if (tid == 0) atomicAdd(&sse[t], wsum[0] + wsum[1] + wsum[2] + wsum[3]);
}

// ---------------------------------------------------------------------------
// Kernel B: tails + 2 tiny head matmuls. One wave.
// d_out = [ head_out (64) | tails (64) ]
// ---------------------------------------------------------------------------
__global__ __launch_bounds__(64) void kitnet_head(
    const float* __restrict__ sse, const float* __restrict__ Wh,
    const float* __restrict__ hbh, const float* __restrict__ vbh,
    float* __restrict__ out)
{
    __shared__ float tl[T_];
    __shared__ float hhL[HH_];
    const int tid = threadIdx.x;

    // tails[t] = log(sqrt(mean)) = 0.5*log(sse/(B*C))
    const float tail = 0.5f * logf(sse[tid] * (1.0f / ((float)B_ * (float)C_)));
    tl[tid] = tail;
    out[T_ + tid] = tail;
    __syncthreads();

    if (tid < HH_) {
        float acc = hbh[tid];
        #pragma unroll 8
        for (int t = 0; t < T_; ++t) acc += tl[t] * Wh[t * HH_ + tid];
        hhL[tid] = acc;
    }
    __syncthreads();

    float ho = vbh[tid];
    #pragma unroll 8
    for (int j = 0; j < HH_; ++j) ho += hhL[j] * Wh[tid * HH_ + j];
    out[tid] = ho;
}

extern "C" void kernel_launch(void* const* d_in, const int* in_sizes, int n_in,
                              void* d_out, int out_size, void* d_ws, size_t ws_size,
                              hipStream_t stream)
{
    const float* x        = (const float*)d_in[0];
    const int*   clusters = (const int*)  d_in[1];
    const float* Wt       = (const float*)d_in[2];
    const float* hb       = (const float*)d_in[3];
    const float* vb       = (const float*)d_in[4];
    const float* Wh       = (const float*)d_in[5];
    const float* hbh      = (const float*)d_in[6];
    const float* vbh      = (const float*)d_in[7];
    float* out = (float*)d_out;
    float* sse = (float*)d_ws;   // T_ floats of scratch

    hipMemsetAsync(sse, 0, T_ * sizeof(float), stream);
    kitnet_main<<<dim3(T_ * (B_ / ROWS)), dim3(256), 0, stream>>>(x, clusters, Wt, hb, vb, sse);
    kitnet_head<<<dim3(1), dim3(64), 0, stream>>>(sse, Wh, hbh, vbh, out);
}